// Round 3
// baseline (416.962 us; speedup 1.0000x reference)
//
#include <hip/hip_runtime.h>
#include <hip/hip_bf16.h>

// Problem constants (match reference)
#define G_     64
#define NK     3
#define NB     64
#define IH     512
#define IW     512
#define NC     3
#define HG_    128
#define HL_    128
#define D_IN_    (NK * G_ * G_ * NC)   // 36864
#define D_SCALE  (G_ * G_ * NC)        // 12288
#define DCHUNK   128
#define NCHUNK   (D_IN_ / DCHUNK)      // 288

__global__ void zero_acc(float* __restrict__ acc) {
    int i = blockIdx.x * 256 + threadIdx.x;
    if (i < NB * HG_) acc[i] = 0.0f;
}

// One block per 128-wide d-chunk (288 blocks). Each block:
//  1) computes phi[b=0..63][dd=0..127] into LDS (fp32, exact avg-pool)
//  2) register-tiled GEMV vs W1 chunk (thread = 8 batches x 4 outputs)
//  3) atomicAdd fp32 partials into acc[64][128]
__global__ __launch_bounds__(256) void glimpse_gemm(
    const float* __restrict__ x,    // fp32, (64,512,512,3)
    const float* __restrict__ l,    // fp32, (64,2)
    const float* __restrict__ W1,   // fp32, (36864,128)
    float* __restrict__ acc)        // (64,128) fp32
{
    __shared__ float phi_s[NB][DCHUNK];      // 32 KB
    __shared__ int cx_s[NB], cy_s[NB];

    const int tid = threadIdx.x;
    const int d0 = blockIdx.x * DCHUNK;

    if (tid < NB) {
        float lx = l[tid * 2 + 0];
        float ly = l[tid * 2 + 1];
        // match reference: (0.5*(l+1.0)*512).astype(int32) — single rounding
        // at (l+1.0f); *0.5 and *512 are exact; trunc toward zero (value >= 0)
        cx_s[tid] = (int)((0.5f * (lx + 1.0f)) * 512.0f);
        cy_s[tid] = (int)((0.5f * (ly + 1.0f)) * 512.0f);
    }
    __syncthreads();

    // chunk lies entirely within one scale (12288 % 128 == 0)
    const int k = d0 / D_SCALE;
    const int f = 1 << k;                    // pool factor 1/2/4
    const int hf = 32 * f;                   // size/2
    const float inv = 1.0f / (float)(f * f);

    for (int i = tid; i < NB * DCHUNK; i += 256) {
        int b  = i >> 7;
        int dd = i & (DCHUNK - 1);
        int r  = d0 + dd - k * D_SCALE;      // ((gy*64)+gx)*3 + c
        int gy = r / (G_ * NC);
        int r2 = r - gy * (G_ * NC);
        int gx = r2 / NC;
        int c  = r2 - gx * NC;
        int by = cy_s[b] - hf + gy * f;      // top row of pooled cell (unpadded)
        int bx = cx_s[b] - hf + gx * f;
        float s = 0.0f;
        for (int dy = 0; dy < f; ++dy) {
            int y = by + dy;
            if ((unsigned)y >= (unsigned)IH) continue;   // pad region = 0
            size_t rowbase = (((size_t)b * IH + y) * IW) * NC + c;
            for (int dx = 0; dx < f; ++dx) {
                int xx = bx + dx;
                if ((unsigned)xx >= (unsigned)IW) continue;
                s += x[rowbase + (size_t)xx * NC];
            }
        }
        phi_s[b][dd] = s * inv;
    }
    __syncthreads();

    // GEMV micro-tile: 256 threads cover 64b x 128h as (8 bgroups) x (32 hgroups of 4)
    const int h0 = (tid & 31) * 4;
    const int b0 = (tid >> 5) * 8;
    float accr[8][4];
#pragma unroll
    for (int i = 0; i < 8; ++i)
#pragma unroll
        for (int j = 0; j < 4; ++j) accr[i][j] = 0.0f;

    const float* wp = W1 + (size_t)d0 * HG_ + h0;
#pragma unroll 4
    for (int dd = 0; dd < DCHUNK; ++dd) {
        float4 wv = *(const float4*)(wp + (size_t)dd * HG_);  // 16B coalesced
#pragma unroll
        for (int i = 0; i < 8; ++i) {
            float p = phi_s[b0 + i][dd];     // wave-broadcast LDS read
            accr[i][0] = fmaf(p, wv.x, accr[i][0]);
            accr[i][1] = fmaf(p, wv.y, accr[i][1]);
            accr[i][2] = fmaf(p, wv.z, accr[i][2]);
            accr[i][3] = fmaf(p, wv.w, accr[i][3]);
        }
    }
#pragma unroll
    for (int i = 0; i < 8; ++i)
#pragma unroll
        for (int j = 0; j < 4; ++j)
            atomicAdd(&acc[(b0 + i) * HG_ + h0 + j], accr[i][j]);
}

// bias + relu on phi branch, tiny l@W2 branch, concat, fp32 store
__global__ void epilogue(
    const float* __restrict__ acc,
    const float* __restrict__ l,
    const float* __restrict__ b1,
    const float* __restrict__ W2,
    const float* __restrict__ b2,
    float* __restrict__ out)
{
    int idx = blockIdx.x * 256 + threadIdx.x;   // 0..16383
    if (idx >= NB * (HG_ + HL_)) return;
    int b = idx >> 8;
    int h = idx & 255;
    float v;
    if (h < HG_) {
        v = acc[b * HG_ + h] + b1[h];
    } else {
        int hh = h - HG_;
        float l0 = l[b * 2 + 0];
        float l1 = l[b * 2 + 1];
        v = fmaf(l1, W2[HL_ + hh], fmaf(l0, W2[hh], b2[hh]));
    }
    out[idx] = fmaxf(v, 0.0f);
}

extern "C" void kernel_launch(void* const* d_in, const int* in_sizes, int n_in,
                              void* d_out, int out_size, void* d_ws, size_t ws_size,
                              hipStream_t stream) {
    const float* x  = (const float*)d_in[0];
    const float* l  = (const float*)d_in[1];
    const float* W1 = (const float*)d_in[2];
    const float* b1 = (const float*)d_in[3];
    const float* W2 = (const float*)d_in[4];
    const float* b2 = (const float*)d_in[5];
    float* out = (float*)d_out;
    float* acc = (float*)d_ws;                   // 64*128 fp32 = 32 KB

    zero_acc<<<(NB * HG_ + 255) / 256, 256, 0, stream>>>(acc);
    glimpse_gemm<<<NCHUNK, 256, 0, stream>>>(x, l, W1, acc);
    epilogue<<<(NB * (HG_ + HL_) + 255) / 256, 256, 0, stream>>>(acc, l, b1, W2, b2, out);
}

// Round 4
// 294.819 us; speedup vs baseline: 1.4143x; 1.4143x over previous
//
#include <hip/hip_runtime.h>
#include <hip/hip_bf16.h>

// Problem constants (match reference)
#define G_     64
#define NK     3
#define NB     64
#define IH     512
#define IW     512
#define NC     3
#define HG_    128
#define HL_    128
#define D_IN_    (NK * G_ * G_ * NC)   // 36864
#define D_SCALE  (G_ * G_ * NC)        // 12288
#define KCH      256                   // d per chunk (48 chunks per scale)
#define NCHUNK   (D_IN_ / KCH)         // 144
#define BSPLIT   4                     // batch groups of 16
#define NBLK     (NCHUNK * BSPLIT)     // 576 blocks

__global__ void zero_acc(float* __restrict__ acc) {
    int i = blockIdx.x * 256 + threadIdx.x;
    if (i < NB * HG_) acc[i] = 0.0f;
}

// Templated per-scale body: F is the pooling factor (1/2/4) at COMPILE TIME so
// the F*F gather loads fully unroll and stay in flight (round-3 lesson: runtime
// F serialized ~512 dependent ~400-cycle loads per thread -> 186us latency wall).
template <int F>
__device__ __forceinline__ void scale_body(
    const float* __restrict__ x, const float* __restrict__ l,
    const float* __restrict__ W1, float* __restrict__ acc,
    int roff, int d0, int b0,
    float (&phi_s)[16][KCH], int* cx_s, int* cy_s)
{
    const int tid = threadIdx.x;
    if (tid < 16) {
        float lx = l[(b0 + tid) * 2 + 0];
        float ly = l[(b0 + tid) * 2 + 1];
        // match reference: (0.5*(l+1.0)*512).astype(int32); single rounding at
        // (l+1.0f), *0.5 and *512 exact, trunc toward zero (value >= 0)
        cx_s[tid] = (int)((0.5f * (lx + 1.0f)) * 512.0f);
        cy_s[tid] = (int)((0.5f * (ly + 1.0f)) * 512.0f);
    }
    __syncthreads();

    // ---- extraction: thread owns dd = tid for all 16 batches ----
    const int r   = roff + tid;          // within-scale index: ((gy*64)+gx)*3+c
    const int gy  = r / (G_ * NC);
    const int rem = r - gy * (G_ * NC);
    const int gx  = rem / NC;
    const int c   = rem - gx * NC;
    constexpr float inv = 1.0f / (float)(F * F);

    for (int j = 0; j < 16; ++j) {
        const int b  = b0 + j;
        const int by = cy_s[j] - 32 * F + gy * F;   // top row of pooled cell
        const int bx = cx_s[j] - 32 * F + gx * F;
        const float* bimg = x + (size_t)b * (IH * IW * NC) + c;
        float s = 0.0f;
#pragma unroll
        for (int dy = 0; dy < F; ++dy) {
            const int y = by + dy;
            const bool yok = (unsigned)y < (unsigned)IH;
#pragma unroll
            for (int dx = 0; dx < F; ++dx) {
                const int xx = bx + dx;
                const bool ok = yok && ((unsigned)xx < (unsigned)IW);
                // exec-masked load + cndmask; OOB lanes never access memory
                s += ok ? bimg[(size_t)y * (IW * NC) + xx * NC] : 0.0f;
            }
        }
        phi_s[j][tid] = s * inv;
    }
    __syncthreads();

    // ---- GEMV: 256 threads = 32 h-lanes(x4) * 8 b-groups(x2) over 16b x 128h ----
    const int h0 = (tid & 31) * 4;
    const int bl = (tid >> 5) * 2;
    float a0[4] = {0, 0, 0, 0}, a1[4] = {0, 0, 0, 0};
    const float* wp = W1 + (size_t)d0 * HG_ + h0;
    const float4* prow0 = (const float4*)phi_s[bl];
    const float4* prow1 = (const float4*)phi_s[bl + 1];

    for (int t = 0; t < KCH / 4; ++t) {
        float4 p0v = prow0[t];           // ds_read_b128
        float4 p1v = prow1[t];
#pragma unroll
        for (int u = 0; u < 4; ++u) {
            float4 wv = *(const float4*)(wp + (size_t)(4 * t + u) * HG_);  // 16B coalesced
            float p0 = (&p0v.x)[u];
            float p1 = (&p1v.x)[u];
            a0[0] = fmaf(p0, wv.x, a0[0]);
            a0[1] = fmaf(p0, wv.y, a0[1]);
            a0[2] = fmaf(p0, wv.z, a0[2]);
            a0[3] = fmaf(p0, wv.w, a0[3]);
            a1[0] = fmaf(p1, wv.x, a1[0]);
            a1[1] = fmaf(p1, wv.y, a1[1]);
            a1[2] = fmaf(p1, wv.z, a1[2]);
            a1[3] = fmaf(p1, wv.w, a1[3]);
        }
    }
#pragma unroll
    for (int jj = 0; jj < 4; ++jj) {
        atomicAdd(&acc[(b0 + bl) * HG_ + h0 + jj], a0[jj]);
        atomicAdd(&acc[(b0 + bl + 1) * HG_ + h0 + jj], a1[jj]);
    }
}

// 576 blocks: blockIdx = chunkGlobal*4 + bgrp; chunkGlobal 0..143 (48 per scale)
__global__ __launch_bounds__(256) void fused(
    const float* __restrict__ x, const float* __restrict__ l,
    const float* __restrict__ W1, float* __restrict__ acc)
{
    __shared__ float phi_s[16][KCH];     // 16 KB
    __shared__ int cx_s[16], cy_s[16];

    const int chunkGlobal = blockIdx.x >> 2;
    const int b0 = (blockIdx.x & 3) * 16;
    const int d0 = chunkGlobal * KCH;            // global d base (scales contiguous)
    const int chunkLocal = chunkGlobal % 48;
    const int roff = chunkLocal * KCH;           // within-scale offset

    if (chunkGlobal < 48) {
        scale_body<1>(x, l, W1, acc, roff, d0, b0, phi_s, cx_s, cy_s);
    } else if (chunkGlobal < 96) {
        scale_body<2>(x, l, W1, acc, roff, d0, b0, phi_s, cx_s, cy_s);
    } else {
        scale_body<4>(x, l, W1, acc, roff, d0, b0, phi_s, cx_s, cy_s);
    }
}

// bias + relu on phi branch, tiny l@W2 branch, concat, fp32 store
__global__ void epilogue(
    const float* __restrict__ acc,
    const float* __restrict__ l,
    const float* __restrict__ b1,
    const float* __restrict__ W2,
    const float* __restrict__ b2,
    float* __restrict__ out)
{
    int idx = blockIdx.x * 256 + threadIdx.x;   // 0..16383
    if (idx >= NB * (HG_ + HL_)) return;
    int b = idx >> 8;
    int h = idx & 255;
    float v;
    if (h < HG_) {
        v = acc[b * HG_ + h] + b1[h];
    } else {
        int hh = h - HG_;
        float l0 = l[b * 2 + 0];
        float l1 = l[b * 2 + 1];
        v = fmaf(l1, W2[HL_ + hh], fmaf(l0, W2[hh], b2[hh]));
    }
    out[idx] = fmaxf(v, 0.0f);
}

extern "C" void kernel_launch(void* const* d_in, const int* in_sizes, int n_in,
                              void* d_out, int out_size, void* d_ws, size_t ws_size,
                              hipStream_t stream) {
    const float* x  = (const float*)d_in[0];
    const float* l  = (const float*)d_in[1];
    const float* W1 = (const float*)d_in[2];
    const float* b1 = (const float*)d_in[3];
    const float* W2 = (const float*)d_in[4];
    const float* b2 = (const float*)d_in[5];
    float* out = (float*)d_out;
    float* acc = (float*)d_ws;                   // 64*128 fp32 = 32 KB

    zero_acc<<<(NB * HG_ + 255) / 256, 256, 0, stream>>>(acc);
    fused<<<NBLK, 256, 0, stream>>>(x, l, W1, acc);
    epilogue<<<(NB * (HG_ + HL_) + 255) / 256, 256, 0, stream>>>(acc, l, b1, W2, b2, out);
}

// Round 5
// 293.733 us; speedup vs baseline: 1.4195x; 1.0037x over previous
//
#include <hip/hip_runtime.h>
#include <hip/hip_bf16.h>

// Problem constants (match reference)
#define G_     64
#define NK     3
#define NB     64
#define IH     512
#define IW     512
#define NC     3
#define HG_    128
#define HL_    128
#define D_IN_    (NK * G_ * G_ * NC)   // 36864
#define D_SCALE  (G_ * G_ * NC)        // 12288
#define KCH      128                   // d per chunk (96 chunks per scale)
#define NCHUNK   (D_IN_ / KCH)         // 288
#define BSPLIT   4                     // batch groups of 16
#define NBLK     (NCHUNK * BSPLIT)     // 1152 blocks (~4.5 waves/SIMD)

__global__ void zero_acc(float* __restrict__ acc) {
    int i = blockIdx.x * 256 + threadIdx.x;
    if (i < NB * HG_) acc[i] = 0.0f;
}

// F = pooling factor (compile-time: loads unroll and stay in flight).
// Extraction mapping: thread = (dd = tid&127, half = tid>>7); computes its
// (gy,gx,c) ONCE, then loops 8 batches with JU-deep unroll so JU*F*F
// independent loads are outstanding (R4 lesson: serial batch rounds were the
// latency wall).
template <int F>
__device__ __forceinline__ void scale_body(
    const float* __restrict__ x, const float* __restrict__ l,
    const float* __restrict__ W1, float* __restrict__ acc,
    int roff, int d0, int b0,
    float (&phi_s)[16][KCH], int* cx_s, int* cy_s)
{
    const int tid = threadIdx.x;
    if (tid < 16) {
        float lx = l[(b0 + tid) * 2 + 0];
        float ly = l[(b0 + tid) * 2 + 1];
        // match reference: (0.5*(l+1.0)*512).astype(int32); single rounding at
        // (l+1.0f), *0.5 and *512 exact, trunc toward zero (value >= 0..511)
        cx_s[tid] = (int)((0.5f * (lx + 1.0f)) * 512.0f);
        cy_s[tid] = (int)((0.5f * (ly + 1.0f)) * 512.0f);
    }
    __syncthreads();

    // ---- extraction ----
    const int dd   = tid & (KCH - 1);
    const int jb0  = (tid >> 7) * 8;         // local batch 0..7 or 8..15
    const int r    = roff + dd;              // within-scale: ((gy*64)+gx)*3+c
    const int gy   = r / (G_ * NC);
    const int rem  = r - gy * (G_ * NC);
    const int gx   = rem / NC;
    const int c    = rem - gx * NC;
    constexpr float inv = 1.0f / (float)(F * F);
    constexpr int JU = (F == 4) ? 2 : 8;     // 32 / 32 / 8 loads in flight

#pragma unroll 1
    for (int jo = 0; jo < 8; jo += JU) {
        float sums[JU];
#pragma unroll
        for (int ji = 0; ji < JU; ++ji) {
            const int jb = jb0 + jo + ji;
            const int b  = b0 + jb;
            const int by = cy_s[jb] - 32 * F + gy * F;
            const int bx = cx_s[jb] - 32 * F + gx * F;
            const float* bimg = x + (size_t)b * (IH * IW * NC) + c;
            float s = 0.0f;
#pragma unroll
            for (int dy = 0; dy < F; ++dy) {
                const int y = by + dy;
                const bool yok = (unsigned)y < (unsigned)IH;
#pragma unroll
                for (int dx = 0; dx < F; ++dx) {
                    const int xx = bx + dx;
                    const bool ok = yok && ((unsigned)xx < (unsigned)IW);
                    s += ok ? bimg[(size_t)y * (IW * NC) + xx * NC] : 0.0f;
                }
            }
            sums[ji] = s;
        }
#pragma unroll
        for (int ji = 0; ji < JU; ++ji)
            phi_s[jb0 + jo + ji][dd] = sums[ji] * inv;
    }
    __syncthreads();

    // ---- GEMV: 256 threads = 32 h-lanes(x4) * 8 pairs of batches ----
    const int h0 = (tid & 31) * 4;
    const int bl = (tid >> 5) * 2;
    float a0[4] = {0, 0, 0, 0}, a1[4] = {0, 0, 0, 0};
    const float* wp = W1 + (size_t)d0 * HG_ + h0;
    const float4* prow0 = (const float4*)phi_s[bl];
    const float4* prow1 = (const float4*)phi_s[bl + 1];

#pragma unroll 2
    for (int t = 0; t < KCH / 4; ++t) {
        float4 p0v = prow0[t];               // ds_read_b128, same-addr broadcast
        float4 p1v = prow1[t];
#pragma unroll
        for (int u = 0; u < 4; ++u) {
            float4 wv = *(const float4*)(wp + (size_t)(4 * t + u) * HG_);
            float p0 = (&p0v.x)[u];
            float p1 = (&p1v.x)[u];
            a0[0] = fmaf(p0, wv.x, a0[0]);
            a0[1] = fmaf(p0, wv.y, a0[1]);
            a0[2] = fmaf(p0, wv.z, a0[2]);
            a0[3] = fmaf(p0, wv.w, a0[3]);
            a1[0] = fmaf(p1, wv.x, a1[0]);
            a1[1] = fmaf(p1, wv.y, a1[1]);
            a1[2] = fmaf(p1, wv.z, a1[2]);
            a1[3] = fmaf(p1, wv.w, a1[3]);
        }
    }
#pragma unroll
    for (int jj = 0; jj < 4; ++jj) {
        atomicAdd(&acc[(b0 + bl) * HG_ + h0 + jj], a0[jj]);
        atomicAdd(&acc[(b0 + bl + 1) * HG_ + h0 + jj], a1[jj]);
    }
}

// 1152 blocks: blockIdx = chunkGlobal*4 + bgrp; chunkGlobal 0..287 (96/scale)
__global__ __launch_bounds__(256) void fused(
    const float* __restrict__ x, const float* __restrict__ l,
    const float* __restrict__ W1, float* __restrict__ acc)
{
    __shared__ float phi_s[16][KCH];     // 8 KB
    __shared__ int cx_s[16], cy_s[16];

    const int chunkGlobal = blockIdx.x >> 2;
    const int b0 = (blockIdx.x & 3) * 16;
    const int d0 = chunkGlobal * KCH;            // global d base
    const int chunkLocal = chunkGlobal % 96;
    const int roff = chunkLocal * KCH;           // within-scale offset

    if (chunkGlobal < 96) {
        scale_body<1>(x, l, W1, acc, roff, d0, b0, phi_s, cx_s, cy_s);
    } else if (chunkGlobal < 192) {
        scale_body<2>(x, l, W1, acc, roff, d0, b0, phi_s, cx_s, cy_s);
    } else {
        scale_body<4>(x, l, W1, acc, roff, d0, b0, phi_s, cx_s, cy_s);
    }
}

// bias + relu on phi branch, tiny l@W2 branch, concat, fp32 store
__global__ void epilogue(
    const float* __restrict__ acc,
    const float* __restrict__ l,
    const float* __restrict__ b1,
    const float* __restrict__ W2,
    const float* __restrict__ b2,
    float* __restrict__ out)
{
    int idx = blockIdx.x * 256 + threadIdx.x;   // 0..16383
    if (idx >= NB * (HG_ + HL_)) return;
    int b = idx >> 8;
    int h = idx & 255;
    float v;
    if (h < HG_) {
        v = acc[b * HG_ + h] + b1[h];
    } else {
        int hh = h - HG_;
        float l0 = l[b * 2 + 0];
        float l1 = l[b * 2 + 1];
        v = fmaf(l1, W2[HL_ + hh], fmaf(l0, W2[hh], b2[hh]));
    }
    out[idx] = fmaxf(v, 0.0f);
}

extern "C" void kernel_launch(void* const* d_in, const int* in_sizes, int n_in,
                              void* d_out, int out_size, void* d_ws, size_t ws_size,
                              hipStream_t stream) {
    const float* x  = (const float*)d_in[0];
    const float* l  = (const float*)d_in[1];
    const float* W1 = (const float*)d_in[2];
    const float* b1 = (const float*)d_in[3];
    const float* W2 = (const float*)d_in[4];
    const float* b2 = (const float*)d_in[5];
    float* out = (float*)d_out;
    float* acc = (float*)d_ws;                   // 64*128 fp32 = 32 KB

    zero_acc<<<(NB * HG_ + 255) / 256, 256, 0, stream>>>(acc);
    fused<<<NBLK, 256, 0, stream>>>(x, l, W1, acc);
    epilogue<<<(NB * (HG_ + HL_) + 255) / 256, 256, 0, stream>>>(acc, l, b1, W2, b2, out);
}

// Round 6
// 290.331 us; speedup vs baseline: 1.4362x; 1.0117x over previous
//
#include <hip/hip_runtime.h>
#include <hip/hip_bf16.h>

// Problem constants (match reference)
#define G_     64
#define NK     3
#define NB     64
#define IH     512
#define IW     512
#define NC     3
#define HG_    128
#define HL_    128
#define D_IN_    (NK * G_ * G_ * NC)   // 36864
#define D_SCALE  (G_ * G_ * NC)        // 12288
#define KCH      128                   // d per chunk (96 chunks per scale)
#define NCHUNK   (D_IN_ / KCH)         // 288
#define BSPLIT   4                     // batch groups of 16
#define NBLK     (NCHUNK * BSPLIT)     // 1152 blocks
#define PSTRIDE  (NB * HG_)            // 8192 floats per chunk-slice of P

// F = pooling factor (compile-time so the F*F gather unrolls; R3 lesson).
// R5 lesson: atomics were the floor -> stage-1 now writes private partials.
template <int F>
__device__ __forceinline__ void scale_body(
    const float* __restrict__ x, const float* __restrict__ l,
    const float* __restrict__ W1, float* __restrict__ P,
    int roff, int d0, int b0, int chunkGlobal,
    float (&phi_s)[16][KCH], int* cx_s, int* cy_s)
{
    const int tid = threadIdx.x;
    if (tid < 16) {
        float lx = l[(b0 + tid) * 2 + 0];
        float ly = l[(b0 + tid) * 2 + 1];
        // match reference: (0.5*(l+1.0)*512).astype(int32); single rounding at
        // (l+1.0f), *0.5 and *512 exact, trunc toward zero
        cx_s[tid] = (int)((0.5f * (lx + 1.0f)) * 512.0f);
        cy_s[tid] = (int)((0.5f * (ly + 1.0f)) * 512.0f);
    }
    __syncthreads();

    // ---- extraction: thread = (dd, batch-half); one (gy,gx,c) per thread ----
    const int dd   = tid & (KCH - 1);
    const int jb0  = (tid >> 7) * 8;
    const int r    = roff + dd;              // within-scale: ((gy*64)+gx)*3+c
    const int gy   = r / (G_ * NC);
    const int rem  = r - gy * (G_ * NC);
    const int gx   = rem / NC;
    const int c    = rem - gx * NC;
    constexpr float inv = 1.0f / (float)(F * F);
    constexpr int JU = (F == 4) ? 2 : 8;     // keep ~16-32 loads in flight

#pragma unroll 1
    for (int jo = 0; jo < 8; jo += JU) {
        float sums[JU];
#pragma unroll
        for (int ji = 0; ji < JU; ++ji) {
            const int jb = jb0 + jo + ji;
            const int b  = b0 + jb;
            const int by = cy_s[jb] - 32 * F + gy * F;
            const int bx = cx_s[jb] - 32 * F + gx * F;
            const float* bimg = x + (size_t)b * (IH * IW * NC) + c;
            float s = 0.0f;
#pragma unroll
            for (int dy = 0; dy < F; ++dy) {
                const int y = by + dy;
                const bool yok = (unsigned)y < (unsigned)IH;
#pragma unroll
                for (int dx = 0; dx < F; ++dx) {
                    const int xx = bx + dx;
                    const bool ok = yok && ((unsigned)xx < (unsigned)IW);
                    s += ok ? bimg[(size_t)y * (IW * NC) + xx * NC] : 0.0f;
                }
            }
            sums[ji] = s;
        }
#pragma unroll
        for (int ji = 0; ji < JU; ++ji)
            phi_s[jb0 + jo + ji][dd] = sums[ji] * inv;
    }
    __syncthreads();

    // ---- GEMV: 256 threads = 32 h-lanes(x4) * 8 pairs of batches ----
    const int h0 = (tid & 31) * 4;
    const int bl = (tid >> 5) * 2;
    float a0[4] = {0, 0, 0, 0}, a1[4] = {0, 0, 0, 0};
    const float* wp = W1 + (size_t)d0 * HG_ + h0;
    const float4* prow0 = (const float4*)phi_s[bl];
    const float4* prow1 = (const float4*)phi_s[bl + 1];

#pragma unroll 2
    for (int t = 0; t < KCH / 4; ++t) {
        float4 p0v = prow0[t];               // ds_read_b128
        float4 p1v = prow1[t];
#pragma unroll
        for (int u = 0; u < 4; ++u) {
            float4 wv = *(const float4*)(wp + (size_t)(4 * t + u) * HG_);
            float p0 = (&p0v.x)[u];
            float p1 = (&p1v.x)[u];
            a0[0] = fmaf(p0, wv.x, a0[0]);
            a0[1] = fmaf(p0, wv.y, a0[1]);
            a0[2] = fmaf(p0, wv.z, a0[2]);
            a0[3] = fmaf(p0, wv.w, a0[3]);
            a1[0] = fmaf(p1, wv.x, a1[0]);
            a1[1] = fmaf(p1, wv.y, a1[1]);
            a1[2] = fmaf(p1, wv.z, a1[2]);
            a1[3] = fmaf(p1, wv.w, a1[3]);
        }
    }
    // coalesced float4 partial stores — NO atomics (R5 lesson)
    float* pb = P + (size_t)chunkGlobal * PSTRIDE + (b0 + bl) * HG_ + h0;
    *(float4*)pb            = make_float4(a0[0], a0[1], a0[2], a0[3]);
    *(float4*)(pb + HG_)    = make_float4(a1[0], a1[1], a1[2], a1[3]);
}

// 1152 blocks: blockIdx = chunkGlobal*4 + bgrp; chunkGlobal 0..287 (96/scale)
__global__ __launch_bounds__(256) void fused(
    const float* __restrict__ x, const float* __restrict__ l,
    const float* __restrict__ W1, float* __restrict__ P)
{
    __shared__ float phi_s[16][KCH];     // 8 KB
    __shared__ int cx_s[16], cy_s[16];

    const int chunkGlobal = blockIdx.x >> 2;
    const int b0 = (blockIdx.x & 3) * 16;
    const int d0 = chunkGlobal * KCH;
    const int chunkLocal = chunkGlobal % 96;
    const int roff = chunkLocal * KCH;

    if (chunkGlobal < 96) {
        scale_body<1>(x, l, W1, P, roff, d0, b0, chunkGlobal, phi_s, cx_s, cy_s);
    } else if (chunkGlobal < 192) {
        scale_body<2>(x, l, W1, P, roff, d0, b0, chunkGlobal, phi_s, cx_s, cy_s);
    } else {
        scale_body<4>(x, l, W1, P, roff, d0, b0, chunkGlobal, phi_s, cx_s, cy_s);
    }
}

// Stage 2: one block per batch. Threads 0..127 and 128..255 each sum 144
// chunk-partials for h = t&127 (coalesced, stride 32KB), LDS-combine, then
// half 0 emits phi branch and half 1 emits the trivial l branch.
__global__ __launch_bounds__(256) void reduce_epilogue(
    const float* __restrict__ P,
    const float* __restrict__ l,
    const float* __restrict__ b1,
    const float* __restrict__ W2,
    const float* __restrict__ b2,
    float* __restrict__ out)
{
    __shared__ float red[HG_];
    const int b = blockIdx.x;
    const int t = threadIdx.x;
    const int h = t & (HG_ - 1);
    const int half = t >> 7;             // 0 or 1

    float s = 0.0f;
    const float* p = P + (size_t)(half * 144) * PSTRIDE + b * HG_ + h;
#pragma unroll 8
    for (int c = 0; c < 144; ++c)
        s += p[(size_t)c * PSTRIDE];

    if (half == 1) red[h] = s;
    __syncthreads();

    if (half == 0) {
        out[b * (HG_ + HL_) + h] = fmaxf(s + red[h] + b1[h], 0.0f);
    } else {
        float l0 = l[b * 2 + 0];
        float l1 = l[b * 2 + 1];
        float v = fmaf(l1, W2[HL_ + h], fmaf(l0, W2[h], b2[h]));
        out[b * (HG_ + HL_) + HG_ + h] = fmaxf(v, 0.0f);
    }
}

extern "C" void kernel_launch(void* const* d_in, const int* in_sizes, int n_in,
                              void* d_out, int out_size, void* d_ws, size_t ws_size,
                              hipStream_t stream) {
    const float* x  = (const float*)d_in[0];
    const float* l  = (const float*)d_in[1];
    const float* W1 = (const float*)d_in[2];
    const float* b1 = (const float*)d_in[3];
    const float* W2 = (const float*)d_in[4];
    const float* b2 = (const float*)d_in[5];
    float* out = (float*)d_out;
    float* P = (float*)d_ws;                 // 288*8192 fp32 = 9.4 MB partials

    fused<<<NBLK, 256, 0, stream>>>(x, l, W1, P);
    reduce_epilogue<<<NB, 256, 0, stream>>>(P, l, b1, W2, b2, out);
}